// Round 6
// baseline (744.564 us; speedup 1.0000x reference)
//
#include <hip/hip_runtime.h>
#include <math.h>

typedef __bf16 bf16;
typedef __bf16 bf16x8 __attribute__((ext_vector_type(8)));
typedef float f32x4 __attribute__((ext_vector_type(4)));

// ---------------------------------------------------------------------------
// 8-element loaders -> bf16x8 fragment. fp32 source converts on the fly.
// ---------------------------------------------------------------------------
__device__ inline bf16x8 load8_cvt(const bf16* p) {
    return *reinterpret_cast<const bf16x8*>(p);
}
__device__ inline bf16x8 load8_cvt(const float* p) {
    f32x4 a = *reinterpret_cast<const f32x4*>(p);
    f32x4 b = *reinterpret_cast<const f32x4*>(p + 4);
    bf16x8 r;
    r[0] = (bf16)a[0]; r[1] = (bf16)a[1]; r[2] = (bf16)a[2]; r[3] = (bf16)a[3];
    r[4] = (bf16)b[0]; r[5] = (bf16)b[1]; r[6] = (bf16)b[2]; r[7] = (bf16)b[3];
    return r;
}

// ---------------------------------------------------------------------------
// GEMM: C[M,N] = A[M,K] @ B[K,N], row-major, fp32 accum.
// A,B,C dtypes templated (fp32 in converts at staging; C bf16 or fp32).
// Block = 256 threads (4 waves), tile 64x64, BK=32.
// LDS stride 40 (pad 8): ds_read_b128 rows land 2 lanes/bank (free on CDNA4).
// ---------------------------------------------------------------------------
#define LDSS 40

template <typename TA, typename TB, typename TC>
__global__ __launch_bounds__(256) void gemm_any(
    const TA* __restrict__ A, const TB* __restrict__ B, TC* __restrict__ C,
    int M, int N, int K)
{
    __shared__ __align__(16) bf16 As[64 * LDSS];
    __shared__ __align__(16) bf16 Bs[64 * LDSS];

    const int tid  = threadIdx.x;
    const int lane = tid & 63;
    const int wave = tid >> 6;
    const int quad = lane >> 4;
    const int l16  = lane & 15;

    const int m0 = blockIdx.y * 64;
    const int n0 = blockIdx.x * 64;
    const int wm = (wave & 1) * 32;
    const int wn = (wave >> 1) * 32;

    // staging index maps
    const int ar = tid >> 2, ak = (tid & 3) * 8;   // A: 64 rows x 32 k, 8 elems/thread
    const int bk = tid >> 3, bn = (tid & 7) * 8;   // B: 32 k x 64 n, 8 elems/thread

    f32x4 acc[2][2] = {};

    for (int k0 = 0; k0 < K; k0 += 32) {
        // stage A tile (k-contiguous)
        bf16x8 av = load8_cvt(A + (size_t)(m0 + ar) * K + k0 + ak);
        *reinterpret_cast<bf16x8*>(&As[ar * LDSS + ak]) = av;
        // stage B tile transposed: Bs[n][k]
        bf16x8 bv = load8_cvt(B + (size_t)(k0 + bk) * N + n0 + bn);
        #pragma unroll
        for (int j = 0; j < 8; ++j) Bs[(bn + j) * LDSS + bk] = bv[j];
        __syncthreads();

        bf16x8 afr[2], bfr[2];
        #pragma unroll
        for (int mi = 0; mi < 2; ++mi)
            afr[mi] = *reinterpret_cast<const bf16x8*>(&As[(wm + mi * 16 + l16) * LDSS + quad * 8]);
        #pragma unroll
        for (int ni = 0; ni < 2; ++ni)
            bfr[ni] = *reinterpret_cast<const bf16x8*>(&Bs[(wn + ni * 16 + l16) * LDSS + quad * 8]);
        #pragma unroll
        for (int mi = 0; mi < 2; ++mi)
            #pragma unroll
            for (int ni = 0; ni < 2; ++ni)
                acc[mi][ni] = __builtin_amdgcn_mfma_f32_16x16x32_bf16(
                    afr[mi], bfr[ni], acc[mi][ni], 0, 0, 0);
        __syncthreads();
    }

    #pragma unroll
    for (int mi = 0; mi < 2; ++mi)
        #pragma unroll
        for (int ni = 0; ni < 2; ++ni)
            #pragma unroll
            for (int r = 0; r < 4; ++r) {
                int row = m0 + wm + mi * 16 + quad * 4 + r;
                int col = n0 + wn + ni * 16 + l16;
                C[(size_t)row * N + col] = (TC)acc[mi][ni][r];
            }
}

// ---------------------------------------------------------------------------
// RoPE in-place on [T, H, 128] bf16 buffer. One thread per (t,h,j), j in 0..63.
// logH: 4 for Q (H=16), 2 for K (H=4).
// ---------------------------------------------------------------------------
__global__ void rope_kernel(bf16* __restrict__ X, int logH, int total)
{
    int idx = blockIdx.x * 256 + threadIdx.x;
    if (idx >= total) return;
    int j  = idx & 63;
    int th = idx >> 6;                 // t * H + h
    int t  = th >> logH;

    bf16* p = X + (size_t)th * 128;
    const float NEG_LN1E4_64 = -0.14391155806323211f;  // -ln(10000)/64
    float inv_freq = expf(NEG_LN1E4_64 * (float)j);
    float ang = (float)t * inv_freq;
    float c = cosf(ang), s = sinf(ang);
    float q0 = (float)p[j], q1 = (float)p[j + 64];
    p[j]      = (bf16)(q0 * c - q1 * s);
    p[j + 64] = (bf16)(q1 * c + q0 * s);
}

// ---------------------------------------------------------------------------
// Flash attention, sliding-window causal, GQA.
// Q:[T,16,128] K,V:[T,4,128] Y:[T,16,128] (bf16).
// Grid: (T/64, 16). Block 256 = 4 waves; wave w owns q rows i0+16w..+15.
// All-finite softmax (fast-math-safe).
// ---------------------------------------------------------------------------
__global__ __launch_bounds__(256) void attn_kernel(
    const bf16* __restrict__ Q, const bf16* __restrict__ K,
    const bf16* __restrict__ V, bf16* __restrict__ Y)
{
    const int HQ = 16, HKV = 4, D = 128, W = 1024;
    const float scale = 0.08838834764831845f;  // 1/sqrt(128)
    const float MASKV = -1.0e30f;              // finite mask sentinel

    __shared__ __align__(16) bf16 Vt[128 * LDSS];      // Vt[d][kk]
    __shared__ __align__(16) bf16 Pl[4][16 * LDSS];    // per-wave P[row][col]

    const int tid  = threadIdx.x;
    const int lane = tid & 63;
    const int wave = tid >> 6;
    const int quad = lane >> 4;
    const int l16  = lane & 15;

    const int i0  = blockIdx.x * 64;
    const int h   = blockIdx.y;
    const int kvh = h >> 2;
    const int q0  = i0 + wave * 16;

    // Q fragments: 16 rows x 128 d -> 4 k-chunks of 32
    bf16x8 qf[4];
    {
        const bf16* qp = Q + (size_t)(q0 + l16) * (HQ * D) + h * D + quad * 8;
        #pragma unroll
        for (int c = 0; c < 4; ++c)
            qf[c] = *reinterpret_cast<const bf16x8*>(qp + c * 32);
    }

    f32x4 o[8] = {};
    float m_i[4], l_i[4];
    #pragma unroll
    for (int r = 0; r < 4; ++r) { m_i[r] = MASKV; l_i[r] = 0.f; }

    int k_start = i0 - (W - 1);
    if (k_start < 0) k_start = 0;
    k_start &= ~31;
    const int k_end = i0 + 63;

    const int vk = tid >> 3;          // key within tile 0..31
    const int vd = (tid & 7) * 16;    // d base 0..112

    for (int k0 = k_start; k0 <= k_end; k0 += 32) {
        __syncthreads();  // previous iteration's Vt reads complete
        // stage V tile transposed
        {
            const bf16* vp = V + (size_t)(k0 + vk) * (HKV * D) + kvh * D + vd;
            bf16x8 v0 = *reinterpret_cast<const bf16x8*>(vp);
            bf16x8 v1 = *reinterpret_cast<const bf16x8*>(vp + 8);
            #pragma unroll
            for (int j = 0; j < 8; ++j) {
                Vt[(vd + j) * LDSS + vk]     = v0[j];
                Vt[(vd + 8 + j) * LDSS + vk] = v1[j];
            }
        }
        __syncthreads();

        // S = Q K^T for two 16-key halves
        f32x4 s[2] = {};
        #pragma unroll
        for (int kh = 0; kh < 2; ++kh) {
            const bf16* kp = K + (size_t)(k0 + kh * 16 + l16) * (HKV * D) + kvh * D + quad * 8;
            #pragma unroll
            for (int c = 0; c < 4; ++c) {
                bf16x8 kf = *reinterpret_cast<const bf16x8*>(kp + c * 32);
                s[kh] = __builtin_amdgcn_mfma_f32_16x16x32_bf16(qf[c], kf, s[kh], 0, 0, 0);
            }
        }

        // mask + scale + row max (finite sentinel, explicit ok-mask)
        float sv_[2][4];
        bool  okm[2][4];
        float mt[4];
        #pragma unroll
        for (int r = 0; r < 4; ++r) {
            int qrow = q0 + quad * 4 + r;
            float best = MASKV;
            #pragma unroll
            for (int kh = 0; kh < 2; ++kh) {
                int key = k0 + kh * 16 + l16;
                bool ok = (key <= qrow) && (qrow - key < W);
                float sv = ok ? s[kh][r] * scale : MASKV;
                okm[kh][r] = ok;
                sv_[kh][r] = sv;
                best = fmaxf(best, sv);
            }
            #pragma unroll
            for (int off = 1; off < 16; off <<= 1)
                best = fmaxf(best, __shfl_xor(best, off, 64));
            mt[r] = best;
        }

        // online softmax update — all-finite arithmetic
        #pragma unroll
        for (int r = 0; r < 4; ++r) {
            float mn = fmaxf(m_i[r], mt[r]);
            float alpha = __expf(m_i[r] - mn);   // arg <= 0, finite
            float rowsum = 0.f;
            float pv[2];
            #pragma unroll
            for (int kh = 0; kh < 2; ++kh) {
                pv[kh] = okm[kh][r] ? __expf(sv_[kh][r] - mn) : 0.f;
                rowsum += pv[kh];
            }
            #pragma unroll
            for (int off = 1; off < 16; off <<= 1)
                rowsum += __shfl_xor(rowsum, off, 64);
            m_i[r] = mn;
            l_i[r] = l_i[r] * alpha + rowsum;
            #pragma unroll
            for (int n = 0; n < 8; ++n) o[n][r] *= alpha;
            sv_[0][r] = pv[0];  // reuse as P storage
            sv_[1][r] = pv[1];
        }

        // P -> LDS (wave-private), read back in A-operand layout
        #pragma unroll
        for (int r = 0; r < 4; ++r)
            #pragma unroll
            for (int kh = 0; kh < 2; ++kh)
                Pl[wave][(quad * 4 + r) * LDSS + kh * 16 + l16] = (bf16)sv_[kh][r];

        bf16x8 pf = *reinterpret_cast<const bf16x8*>(&Pl[wave][l16 * LDSS + quad * 8]);
        #pragma unroll
        for (int n = 0; n < 8; ++n) {
            bf16x8 vf = *reinterpret_cast<const bf16x8*>(&Vt[(n * 16 + l16) * LDSS + quad * 8]);
            o[n] = __builtin_amdgcn_mfma_f32_16x16x32_bf16(pf, vf, o[n], 0, 0, 0);
        }
    }

    // epilogue: normalize and store (every row has >=1 valid key: its own)
    #pragma unroll
    for (int r = 0; r < 4; ++r) {
        int row = q0 + quad * 4 + r;
        float inv = (l_i[r] > 0.f) ? 1.f / l_i[r] : 0.f;
        #pragma unroll
        for (int n = 0; n < 8; ++n)
            Y[(size_t)row * (HQ * D) + h * D + n * 16 + l16] = (bf16)(o[n][r] * inv);
    }
}

// ---------------------------------------------------------------------------
extern "C" void kernel_launch(void* const* d_in, const int* in_sizes, int n_in,
                              void* d_out, int out_size, void* d_ws, size_t ws_size,
                              hipStream_t stream)
{
    // Inputs fp32, OUTPUT fp32 (reference dtype). bf16 allowed internally.
    const float* x  = (const float*)d_in[0];
    const float* Wq = (const float*)d_in[1];
    const float* Wk = (const float*)d_in[2];
    const float* Wv = (const float*)d_in[3];
    const float* Wo = (const float*)d_in[4];
    float* out = (float*)d_out;

    // d_out is 32MB as fp32; Q (16MB bf16) staged in its first half, dead
    // before the final GEMM overwrites d_out. Workspace (24MB): K|V|Y.
    char* ws = (char*)d_ws;
    bf16* Qb = (bf16*)d_out;
    bf16* Kb = (bf16*)(ws);
    bf16* Vb = (bf16*)(ws + (4u << 20));
    bf16* Yb = (bf16*)(ws + (8u << 20));

    const int T = 4096, DIM = 2048, NKV = 512;
    dim3 blk(256);

    gemm_any<float, float, bf16><<<dim3(DIM / 64, T / 64), blk, 0, stream>>>(x, Wq, Qb, T, DIM, DIM);
    gemm_any<float, float, bf16><<<dim3(NKV / 64, T / 64), blk, 0, stream>>>(x, Wk, Kb, T, NKV, DIM);
    gemm_any<float, float, bf16><<<dim3(NKV / 64, T / 64), blk, 0, stream>>>(x, Wv, Vb, T, NKV, DIM);

    int qtot = T * 16 * 64, ktot = T * 4 * 64;
    rope_kernel<<<(qtot + 255) / 256, 256, 0, stream>>>(Qb, 4, qtot);
    rope_kernel<<<(ktot + 255) / 256, 256, 0, stream>>>(Kb, 2, ktot);

    attn_kernel<<<dim3(T / 64, 16), blk, 0, stream>>>(Qb, Kb, Vb, Yb);

    gemm_any<bf16, float, float><<<dim3(DIM / 64, T / 64), blk, 0, stream>>>(Yb, Wo, out, T, DIM, DIM);
}

// Round 7
// 533.260 us; speedup vs baseline: 1.3962x; 1.3962x over previous
//
#include <hip/hip_runtime.h>
#include <math.h>

typedef __bf16 bf16;
typedef __bf16 bf16x8 __attribute__((ext_vector_type(8)));
typedef __bf16 bf16x4 __attribute__((ext_vector_type(4)));
typedef float f32x4 __attribute__((ext_vector_type(4)));

// ---------------------------------------------------------------------------
// async global->LDS 16B (direct-to-shared DMA). LDS dest must be
// wave-uniform base + lane*16 — our staging maps guarantee that.
// ---------------------------------------------------------------------------
__device__ __forceinline__ void ldg_lds16(const bf16* g, bf16* l) {
#if __has_builtin(__builtin_amdgcn_global_load_lds)
    __builtin_amdgcn_global_load_lds(
        (const __attribute__((address_space(1))) void*)g,
        (__attribute__((address_space(3))) void*)l, 16, 0, 0);
#else
    *(bf16x8*)l = *(const bf16x8*)g;
#endif
}

// ---------------------------------------------------------------------------
// cvt_x: fp32 -> bf16, 8 elems/thread, coalesced.
// ---------------------------------------------------------------------------
__global__ void cvt_x(const float* __restrict__ X, bf16* __restrict__ Xb, int total8)
{
    int idx = blockIdx.x * 256 + threadIdx.x;
    if (idx >= total8) return;
    const float* p = X + (size_t)idx * 8;
    f32x4 a = *reinterpret_cast<const f32x4*>(p);
    f32x4 b = *reinterpret_cast<const f32x4*>(p + 4);
    bf16x8 r;
    r[0] = (bf16)a[0]; r[1] = (bf16)a[1]; r[2] = (bf16)a[2]; r[3] = (bf16)a[3];
    r[4] = (bf16)b[0]; r[5] = (bf16)b[1]; r[6] = (bf16)b[2]; r[7] = (bf16)b[3];
    *reinterpret_cast<bf16x8*>(Xb + (size_t)idx * 8) = r;
}

// ---------------------------------------------------------------------------
// cvt_wt: W[K=2048][Ncols] fp32 -> Wt[Ncols][2048] bf16 (transpose via LDS).
// block (32,8); grid (Ncols/32, 2048/32).
// ---------------------------------------------------------------------------
__global__ void cvt_wt(const float* __restrict__ W, bf16* __restrict__ Wt, int Ncols)
{
    __shared__ float t[32][33];
    const int n0 = blockIdx.x * 32, k0 = blockIdx.y * 32;
    const int x = threadIdx.x, y = threadIdx.y;
    #pragma unroll
    for (int i = 0; i < 4; ++i)
        t[y + 8 * i][x] = W[(size_t)(k0 + y + 8 * i) * Ncols + n0 + x];
    __syncthreads();
    #pragma unroll
    for (int i = 0; i < 4; ++i)
        Wt[(size_t)(n0 + y + 8 * i) * 2048 + k0 + x] = (bf16)t[x][y + 8 * i];
}

// ---------------------------------------------------------------------------
// gemm_bt: C[M,N] = A[M,K] @ Bt[N,K]^T, bf16 in, fp32 accum.
// m97 structure: 128x128 tile, BK=32, 4 waves of 64x64, global_load_lds x16.
// MODE 1: QKV split epilogue (col tile 0-15 -> Q[T,2048], 16-19 -> K[T,512],
//         20-23 -> Vt[512][T] transposed). MODE 2: fp32 C.
// ---------------------------------------------------------------------------
template <int MODE>
__global__ __launch_bounds__(256) void gemm_bt(
    const bf16* __restrict__ A, const bf16* __restrict__ Bt,
    void* __restrict__ C0, void* __restrict__ C1, void* __restrict__ C2,
    int M, int N, int K)
{
    __shared__ __align__(16) bf16 As[128 * 32];
    __shared__ __align__(16) bf16 Bs[128 * 32];

    const int tid  = threadIdx.x;
    const int lane = tid & 63;
    const int wave = tid >> 6;
    const int quad = lane >> 4;
    const int l16  = lane & 15;

    const int m0 = blockIdx.y * 128;
    const int n0 = blockIdx.x * 128;
    const int wm = (wave >> 1) * 64;
    const int wn = (wave & 1) * 64;

    f32x4 acc[4][4] = {};

    for (int k0 = 0; k0 < K; k0 += 32) {
        #pragma unroll
        for (int p = 0; p < 2; ++p) {
            int u = p * 256 + tid;          // 16B-unit index, lane-contiguous
            int row = u >> 2, kc = u & 3;
            ldg_lds16(A  + (size_t)(m0 + row) * K + k0 + kc * 8, &As[u * 8]);
            ldg_lds16(Bt + (size_t)(n0 + row) * K + k0 + kc * 8, &Bs[u * 8]);
        }
        __syncthreads();

        bf16x8 af[4], bfr[4];
        #pragma unroll
        for (int i = 0; i < 4; ++i) {
            af[i]  = *reinterpret_cast<const bf16x8*>(&As[(wm + i * 16 + l16) * 32 + quad * 8]);
            bfr[i] = *reinterpret_cast<const bf16x8*>(&Bs[(wn + i * 16 + l16) * 32 + quad * 8]);
        }
        #pragma unroll
        for (int mi = 0; mi < 4; ++mi)
            #pragma unroll
            for (int ni = 0; ni < 4; ++ni)
                acc[mi][ni] = __builtin_amdgcn_mfma_f32_16x16x32_bf16(
                    af[mi], bfr[ni], acc[mi][ni], 0, 0, 0);
        __syncthreads();
    }

    #pragma unroll
    for (int mi = 0; mi < 4; ++mi) {
        #pragma unroll
        for (int ni = 0; ni < 4; ++ni) {
            const int row = m0 + wm + mi * 16 + quad * 4;
            const int col = n0 + wn + ni * 16 + l16;
            if (MODE == 2) {
                float* C = (float*)C0;
                #pragma unroll
                for (int r = 0; r < 4; ++r)
                    C[(size_t)(row + r) * N + col] = acc[mi][ni][r];
            } else {
                if (n0 < 2048) {            // Q region
                    bf16* Q = (bf16*)C0;
                    #pragma unroll
                    for (int r = 0; r < 4; ++r)
                        Q[(size_t)(row + r) * 2048 + col] = (bf16)acc[mi][ni][r];
                } else if (n0 < 2560) {     // K region
                    bf16* Kb = (bf16*)C1;
                    #pragma unroll
                    for (int r = 0; r < 4; ++r)
                        Kb[(size_t)(row + r) * 512 + (col - 2048)] = (bf16)acc[mi][ni][r];
                } else {                    // V region -> transposed Vt[d][t]
                    bf16* Vt = (bf16*)C2;
                    bf16x4 v;
                    #pragma unroll
                    for (int r = 0; r < 4; ++r) v[r] = (bf16)acc[mi][ni][r];
                    *reinterpret_cast<bf16x4*>(&Vt[(size_t)(col - 2560) * 4096 + row]) = v;
                }
            }
        }
    }
}

// ---------------------------------------------------------------------------
// RoPE in-place on [T, H, 128] bf16. One thread per (t,h,j), j in 0..63.
// ---------------------------------------------------------------------------
__global__ void rope_kernel(bf16* __restrict__ X, int logH, int total)
{
    int idx = blockIdx.x * 256 + threadIdx.x;
    if (idx >= total) return;
    int j  = idx & 63;
    int th = idx >> 6;
    int t  = th >> logH;

    bf16* p = X + (size_t)th * 128;
    const float NEG_LN1E4_64 = -0.14391155806323211f;  // -ln(10000)/64
    float inv_freq = expf(NEG_LN1E4_64 * (float)j);
    float ang = (float)t * inv_freq;
    float c = cosf(ang), s = sinf(ang);
    float q0 = (float)p[j], q1 = (float)p[j + 64];
    p[j]      = (bf16)(q0 * c - q1 * s);
    p[j + 64] = (bf16)(q1 * c + q0 * s);
}

// ---------------------------------------------------------------------------
// attn_v3: flash attention, sliding window 1024, causal, GQA.
// Q:[T,16,128] K:[T,4,128] Vt:[4*128][T] Y:[T,16,128] (bf16).
// Grid (T/64, 16), 256 thr = 4 independent waves (16 q-rows each).
// NO barriers, NO shared staging: K/V fragments straight from global
// (64B-line-efficient per wave-instruction); wave-private P LDS only.
// 64-key steps amortize the softmax. All-finite math (round-6-proven).
// ---------------------------------------------------------------------------
__global__ __launch_bounds__(256) void attn_v3(
    const bf16* __restrict__ Q, const bf16* __restrict__ K,
    const bf16* __restrict__ Vt, bf16* __restrict__ Y)
{
    const float scale = 0.08838834764831845f;  // 1/sqrt(128)
    const float MASKV = -1.0e30f;

    __shared__ __align__(16) bf16 Pl[4][16 * 72];  // per-wave P[row][64key], pad->72

    const int tid  = threadIdx.x;
    const int lane = tid & 63;
    const int wave = tid >> 6;
    const int quad = lane >> 4;
    const int l16  = lane & 15;

    const int i0  = blockIdx.x * 64;
    const int h   = blockIdx.y;
    const int kvh = h >> 2;
    const int q0  = i0 + wave * 16;
    bf16* Plw = Pl[wave];

    // Q fragments (A-operand): rows q0+l16, k-chunks of 32
    bf16x8 qf[4];
    {
        const bf16* qp = Q + (size_t)(q0 + l16) * 2048 + h * 128 + quad * 8;
        #pragma unroll
        for (int c = 0; c < 4; ++c)
            qf[c] = *reinterpret_cast<const bf16x8*>(qp + c * 32);
    }

    f32x4 o[8] = {};
    float m_i[4], l_i[4];
    #pragma unroll
    for (int r = 0; r < 4; ++r) { m_i[r] = MASKV; l_i[r] = 0.f; }

    int ks = q0 - 1023; if (ks < 0) ks = 0;
    ks &= ~63;
    const int kend = q0 + 15;

    for (int k0 = ks; k0 <= kend; k0 += 64) {
        // S = Q K^T, four 16-key halves
        f32x4 s[4];
        #pragma unroll
        for (int kh = 0; kh < 4; ++kh) {
            f32x4 sv = {};
            const bf16* kp = K + (size_t)(k0 + kh * 16 + l16) * 512 + kvh * 128 + quad * 8;
            #pragma unroll
            for (int c = 0; c < 4; ++c)
                sv = __builtin_amdgcn_mfma_f32_16x16x32_bf16(
                    qf[c], *reinterpret_cast<const bf16x8*>(kp + c * 32), sv, 0, 0, 0);
            s[kh] = sv;
        }

        // mask + scale + row max
        float svv[4][4]; bool okm[4][4]; float mt[4];
        #pragma unroll
        for (int r = 0; r < 4; ++r) {
            int qrow = q0 + quad * 4 + r;
            float best = MASKV;
            #pragma unroll
            for (int kh = 0; kh < 4; ++kh) {
                int key = k0 + kh * 16 + l16;
                bool ok = (key <= qrow) && (qrow - key < 1024);
                float v = ok ? s[kh][r] * scale : MASKV;
                okm[kh][r] = ok;
                svv[kh][r] = v;
                best = fmaxf(best, v);
            }
            #pragma unroll
            for (int off = 1; off < 16; off <<= 1)
                best = fmaxf(best, __shfl_xor(best, off, 64));
            mt[r] = best;
        }

        // online softmax update (all-finite) + P pack
        #pragma unroll
        for (int r = 0; r < 4; ++r) {
            float mn = fmaxf(m_i[r], mt[r]);
            float alpha = __expf(m_i[r] - mn);   // arg <= 0, finite
            float rowsum = 0.f;
            float pv[4];
            #pragma unroll
            for (int kh = 0; kh < 4; ++kh) {
                pv[kh] = okm[kh][r] ? __expf(svv[kh][r] - mn) : 0.f;
                rowsum += pv[kh];
            }
            #pragma unroll
            for (int off = 1; off < 16; off <<= 1)
                rowsum += __shfl_xor(rowsum, off, 64);
            m_i[r] = mn;
            l_i[r] = l_i[r] * alpha + rowsum;
            #pragma unroll
            for (int n = 0; n < 8; ++n) o[n][r] *= alpha;
            #pragma unroll
            for (int kh = 0; kh < 4; ++kh)
                Plw[(quad * 4 + r) * 72 + kh * 16 + l16] = (bf16)pv[kh];
        }

        // P (A-operand) + V (B-operand, straight from global Vt[d][t])
        bf16x8 pf0 = *reinterpret_cast<const bf16x8*>(&Plw[l16 * 72 + quad * 8]);
        bf16x8 pf1 = *reinterpret_cast<const bf16x8*>(&Plw[l16 * 72 + 32 + quad * 8]);
        const bf16* vb = Vt + (size_t)(kvh * 128 + l16) * 4096 + k0 + quad * 8;
        #pragma unroll
        for (int n = 0; n < 8; ++n) {
            bf16x8 v0 = *reinterpret_cast<const bf16x8*>(vb + (size_t)n * 16 * 4096);
            bf16x8 v1 = *reinterpret_cast<const bf16x8*>(vb + (size_t)n * 16 * 4096 + 32);
            o[n] = __builtin_amdgcn_mfma_f32_16x16x32_bf16(pf0, v0, o[n], 0, 0, 0);
            o[n] = __builtin_amdgcn_mfma_f32_16x16x32_bf16(pf1, v1, o[n], 0, 0, 0);
        }
    }

    // epilogue
    #pragma unroll
    for (int r = 0; r < 4; ++r) {
        int row = q0 + quad * 4 + r;
        float inv = (l_i[r] > 0.f) ? 1.f / l_i[r] : 0.f;
        #pragma unroll
        for (int n = 0; n < 8; ++n)
            Y[(size_t)row * 2048 + h * 128 + n * 16 + l16] = (bf16)(o[n][r] * inv);
    }
}

// ---------------------------------------------------------------------------
extern "C" void kernel_launch(void* const* d_in, const int* in_sizes, int n_in,
                              void* d_out, int out_size, void* d_ws, size_t ws_size,
                              hipStream_t stream)
{
    const float* x  = (const float*)d_in[0];
    const float* Wq = (const float*)d_in[1];
    const float* Wk = (const float*)d_in[2];
    const float* Wv = (const float*)d_in[3];
    const float* Wo = (const float*)d_in[4];
    float* out = (float*)d_out;

    const int T = 4096, DIM = 2048;

    // d_out (32MB fp32) hosts bf16 intermediates, all dead before final GEMM:
    //   [0,16M) Qb [T,2048] | [16M,20M) Kb [T,512] | [20M,24M) Vt [512][T]
    char* po = (char*)d_out;
    bf16* Qb = (bf16*)(po);
    bf16* Kb = (bf16*)(po + (16u << 20));
    bf16* Vtb = (bf16*)(po + (20u << 20));

    // ws (peak 28MB): [0,16M) xb -> later Yb ; [16M,28M) Wqkv^T -> later Wo^T
    char* ws = (char*)d_ws;
    bf16* xb    = (bf16*)(ws);
    bf16* Wqkvt = (bf16*)(ws + (16u << 20));
    bf16* Yb    = (bf16*)(ws);                 // reuses xb (dead after QKV GEMM)
    bf16* Wot   = (bf16*)(ws + (16u << 20));   // reuses Wqkv^T (dead after QKV GEMM)

    // 1. convert x -> bf16
    cvt_x<<<dim3(T * DIM / 8 / 256), 256, 0, stream>>>(x, xb, T * DIM / 8);

    // 2. transpose-convert Wq|Wk|Wv -> Wqkv^T [3072][2048]
    dim3 tb(32, 8);
    cvt_wt<<<dim3(2048 / 32, 64), tb, 0, stream>>>(Wq, Wqkvt, 2048);
    cvt_wt<<<dim3(512 / 32, 64),  tb, 0, stream>>>(Wk, Wqkvt + (size_t)2048 * 2048, 512);
    cvt_wt<<<dim3(512 / 32, 64),  tb, 0, stream>>>(Wv, Wqkvt + (size_t)2560 * 2048, 512);

    // 3. fused QKV GEMM: [4096,2048] x [3072,2048]^T -> Qb | Kb | Vt
    gemm_bt<1><<<dim3(3072 / 128, T / 128), 256, 0, stream>>>(
        xb, Wqkvt, Qb, Kb, Vtb, T, 3072, DIM);

    // 4. Wo^T (after QKV GEMM frees the region)
    cvt_wt<<<dim3(2048 / 32, 64), tb, 0, stream>>>(Wo, Wot, 2048);

    // 5. RoPE
    int qtot = T * 16 * 64, ktot = T * 4 * 64;
    rope_kernel<<<(qtot + 255) / 256, 256, 0, stream>>>(Qb, 4, qtot);
    rope_kernel<<<(ktot + 255) / 256, 256, 0, stream>>>(Kb, 2, ktot);

    // 6. attention
    attn_v3<<<dim3(T / 64, 16), 256, 0, stream>>>(Qb, Kb, Vtb, Yb);

    // 7. output projection: [4096,2048] x [2048,2048]^T -> out (fp32)
    gemm_bt<2><<<dim3(2048 / 128, T / 128), 256, 0, stream>>>(
        Yb, Wot, out, nullptr, nullptr, T, 2048, DIM);
}